// Round 1
// baseline (1443.463 us; speedup 1.0000x reference)
//
#include <hip/hip_runtime.h>
#include <hip/hip_bf16.h>
#include <math.h>

// B=8192, D=512, V=64, E=8, hidden (1024,512,256)
// Strategy: all matmuls as bf16 MFMA with hi/lo split (3-product emulation of f32).
// A buffers: [M][2K] bf16 = [hi | lo]. B buffers: [N][2K] bf16 = [hi | lo] (transposed weights).
// GEMM runs K' = 3K tiles: block b=0: Ahi*Bhi, b=1: Alo*Bhi, b=2: Ahi*Blo.

typedef short bf16x8 __attribute__((ext_vector_type(8)));
typedef float f32x4 __attribute__((ext_vector_type(4)));

__device__ __forceinline__ ushort f2bf(float x){
  union { float f; unsigned u; } v; v.f = x;
  unsigned r = v.u + 0x7fffu + ((v.u >> 16) & 1u);
  return (ushort)(r >> 16);
}
__device__ __forceinline__ float bf2f(ushort h){
  union { unsigned u; float f; } v; v.u = ((unsigned)h) << 16; return v.f;
}
__device__ __forceinline__ float elu_f(float x){
  return x > 0.f ? x : expm1f(x);
}

// ---- prep: activations f32 [rows][K] -> [rows][2K] bf16 hi|lo ----
__global__ void prep_act(const float* __restrict__ X, ushort* __restrict__ A,
                         int total, int K){
  int i = blockIdx.x * blockDim.x + threadIdx.x;
  if (i >= total) return;
  int row = i / K, k = i - row * K;
  float x = X[i];
  ushort hi = f2bf(x);
  ushort lo = f2bf(x - bf2f(hi));
  size_t base = (size_t)row * (size_t)(2 * K);
  A[base + k] = hi;
  A[base + K + k] = lo;
}

// ---- prep: weights f32 [E][K][N] -> Bt bf16 [E][N][2K] (transpose + split) ----
__global__ void prep_w(const float* __restrict__ W, ushort* __restrict__ Bt,
                       int K, int N){
  __shared__ float tile[32][33];
  int e = blockIdx.z;
  const float* w = W + (size_t)e * K * N;
  ushort* bt = Bt + (size_t)e * N * 2 * K;
  int n0 = blockIdx.x * 32, k0 = blockIdx.y * 32;
  for (int i = threadIdx.y; i < 32; i += 8)
    tile[i][threadIdx.x] = w[(size_t)(k0 + i) * N + n0 + threadIdx.x];
  __syncthreads();
  for (int j = threadIdx.y; j < 32; j += 8){
    float v = tile[threadIdx.x][j];             // w[k0+tx][n0+j]
    ushort hi = f2bf(v);
    ushort lo = f2bf(v - bf2f(hi));
    size_t base = (size_t)(n0 + j) * (size_t)(2 * K);
    bt[base + k0 + threadIdx.x] = hi;
    bt[base + K + k0 + threadIdx.x] = lo;
  }
}

// ---- main GEMM: C[M,N] = split3(A[M,2K] x Bt[N,2K]^T) + bias, ELU ----
// EPI==0: write split bf16 [M][2N] hi|lo (feeds next layer). EPI==1: write f32 [M][N].
template<int EPI>
__global__ __launch_bounds__(256) void gemm_bt(
    const ushort* __restrict__ A, const ushort* __restrict__ Bt,
    const float* __restrict__ bias, void* __restrict__ Cout,
    int N, int K)
{
  __shared__ __align__(16) ushort As[128][64];   // 16KB
  __shared__ __align__(16) ushort Bs[128][64];   // 16KB
  const int tid = threadIdx.x;
  const int lane = tid & 63;
  const int wave = tid >> 6;
  const int wr = wave >> 1, wc = wave & 1;       // 2x2 waves, 64x64 each
  const int rowBase = blockIdx.y * 128;
  const int colBase = blockIdx.x * 128;
  const int KB = K >> 6;                          // K/64 tiles per section
  const int NT = 3 * KB;
  const int lr = lane & 15;
  const int lk = (lane >> 4) << 3;
  const size_t strideA = (size_t)(2 * K);

  f32x4 acc[4][4];
  #pragma unroll
  for (int m = 0; m < 4; m++)
    #pragma unroll
    for (int n = 0; n < 4; n++)
      acc[m][n] = (f32x4){0.f, 0.f, 0.f, 0.f};

  for (int kt = 0; kt < NT; ++kt){
    int b = kt / KB;
    int inner = kt - b * KB;
    int koffA = ((b == 1) ? K : 0) + (inner << 6);   // blocks: hi, lo, hi
    int koffB = ((b == 2) ? K : 0) + (inner << 6);   // blocks: hi, hi, lo
    __syncthreads();   // previous tile fully consumed before overwrite
    #pragma unroll
    for (int j = 0; j < 4; j++){
      int L = (j << 11) + (tid << 3);   // bf16-element offset within 128x64 tile
      int r = L >> 6, c = L & 63;
      __builtin_amdgcn_global_load_lds(
        (const __attribute__((address_space(1))) void*)(A + (size_t)(rowBase + r) * strideA + koffA + c),
        (__attribute__((address_space(3))) void*)(&As[0][0] + L), 16, 0, 0);
      __builtin_amdgcn_global_load_lds(
        (const __attribute__((address_space(1))) void*)(Bt + (size_t)(colBase + r) * strideA + koffB + c),
        (__attribute__((address_space(3))) void*)(&Bs[0][0] + L), 16, 0, 0);
    }
    __syncthreads();   // vmcnt(0) drained by compiler before barrier
    #pragma unroll
    for (int ks = 0; ks < 2; ks++){
      bf16x8 af[4], bfr[4];
      #pragma unroll
      for (int m = 0; m < 4; m++)
        af[m] = *(const bf16x8*)&As[wr * 64 + m * 16 + lr][ks * 32 + lk];
      #pragma unroll
      for (int n = 0; n < 4; n++)
        bfr[n] = *(const bf16x8*)&Bs[wc * 64 + n * 16 + lr][ks * 32 + lk];
      #pragma unroll
      for (int m = 0; m < 4; m++)
        #pragma unroll
        for (int n = 0; n < 4; n++)
          acc[m][n] = __builtin_amdgcn_mfma_f32_16x16x32_bf16(af[m], bfr[n], acc[m][n], 0, 0, 0);
    }
  }

  // epilogue: C/D layout col=lane&15, row=(lane>>4)*4+reg
  const int r0 = rowBase + wr * 64 + ((lane >> 4) << 2);
  const int c0 = colBase + wc * 64 + lr;
  #pragma unroll
  for (int m = 0; m < 4; m++){
    #pragma unroll
    for (int n = 0; n < 4; n++){
      int col = c0 + n * 16;
      float bv = bias[col];
      #pragma unroll
      for (int r = 0; r < 4; r++){
        int row = r0 + m * 16 + r;
        float v = elu_f(acc[m][n][r] + bv);
        if (EPI == 0){
          ushort hi = f2bf(v);
          ushort lo = f2bf(v - bf2f(hi));
          ushort* C = (ushort*)Cout;
          size_t base = (size_t)row * (size_t)(2 * N);
          C[base + col] = hi;
          C[base + N + col] = lo;
        } else {
          ((float*)Cout)[(size_t)row * N + col] = v;
        }
      }
    }
  }
}

// ---- gate final layer + softmax: wts[B][8] = softmax(g2[B][256] @ gw3[256][8] + gb3) ----
__global__ void gate3_softmax(const float* __restrict__ g2, const float* __restrict__ gw3,
                              const float* __restrict__ gb3, float* __restrict__ wts){
  int row = blockIdx.x * 4 + (threadIdx.x >> 6);
  int lane = threadIdx.x & 63;
  const float* g = g2 + (size_t)row * 256;
  float p[8];
  #pragma unroll
  for (int j = 0; j < 8; j++) p[j] = 0.f;
  for (int k = lane; k < 256; k += 64){
    float x = g[k];
    #pragma unroll
    for (int j = 0; j < 8; j++) p[j] += x * gw3[k * 8 + j];
  }
  #pragma unroll
  for (int j = 0; j < 8; j++){
    #pragma unroll
    for (int s = 32; s > 0; s >>= 1) p[j] += __shfl_xor(p[j], s, 64);
  }
  float mx = -1e30f;
  #pragma unroll
  for (int j = 0; j < 8; j++){ p[j] += gb3[j]; mx = fmaxf(mx, p[j]); }
  float sum = 0.f;
  #pragma unroll
  for (int j = 0; j < 8; j++){ p[j] = expf(p[j] - mx); sum += p[j]; }
  float inv = 1.f / sum;
  #pragma unroll
  for (int j = 0; j < 8; j++)
    if (lane == j) wts[(size_t)row * 8 + j] = p[j] * inv;
}

// ---- expert final layer: ret[B][e] = h2[B][256] @ w3[256] + b3 ----
__global__ void returns_k(const float* __restrict__ h2, const float* __restrict__ w3,
                          const float* __restrict__ b3, float* __restrict__ ret, int e){
  int row = blockIdx.x * 4 + (threadIdx.x >> 6);
  int lane = threadIdx.x & 63;
  const float* h = h2 + (size_t)row * 256;
  float s = 0.f;
  for (int k = lane; k < 256; k += 64) s += h[k] * w3[k];
  #pragma unroll
  for (int m = 32; m > 0; m >>= 1) s += __shfl_xor(s, m, 64);
  if (lane == 0) ret[(size_t)row * 8 + e] = s + b3[0];
}

// ---- final: out[B] = sum_e wts * ret ----
__global__ void combine(const float* __restrict__ wts, const float* __restrict__ ret,
                        float* __restrict__ out){
  int i = blockIdx.x * blockDim.x + threadIdx.x;
  if (i >= 8192) return;
  float s = 0.f;
  #pragma unroll
  for (int j = 0; j < 8; j++) s += wts[(size_t)i * 8 + j] * ret[(size_t)i * 8 + j];
  out[i] = s;
}

extern "C" void kernel_launch(void* const* d_in, const int* in_sizes, int n_in,
                              void* d_out, int out_size, void* d_ws, size_t ws_size,
                              hipStream_t stream){
  const float* obs  = (const float*)d_in[0];
  const float* code = (const float*)d_in[1];
  const float* ew0  = (const float*)d_in[2];
  const float* eb0  = (const float*)d_in[3];
  const float* ew1  = (const float*)d_in[4];
  const float* eb1  = (const float*)d_in[5];
  const float* ew2  = (const float*)d_in[6];
  const float* eb2  = (const float*)d_in[7];
  const float* ew3  = (const float*)d_in[8];
  const float* eb3  = (const float*)d_in[9];
  const float* gw0  = (const float*)d_in[10];
  const float* gb0  = (const float*)d_in[11];
  const float* gw1  = (const float*)d_in[12];
  const float* gb1  = (const float*)d_in[13];
  const float* gw2  = (const float*)d_in[14];
  const float* gb2  = (const float*)d_in[15];
  const float* gw3  = (const float*)d_in[16];
  const float* gb3  = (const float*)d_in[17];

  char* ws = (char*)d_ws;
  size_t off = 0;
  auto alloc = [&](size_t bytes) -> void* {
    void* p = ws + off;
    off += (bytes + 255) & ~(size_t)255;
    return p;
  };
  ushort* A_obs  = (ushort*)alloc(8192ull * 1024 * 2);   // [8192][2*512]
  ushort* A_code = (ushort*)alloc(8192ull * 128 * 2);    // [8192][2*64]
  ushort* B_ew0  = (ushort*)alloc(8ull * 1024 * 1024 * 2); // [8][1024][2*512]
  ushort* B_ew1  = (ushort*)alloc(8ull * 512 * 2048 * 2);  // [8][512][2*1024]
  ushort* B_ew2  = (ushort*)alloc(8ull * 256 * 1024 * 2);  // [8][256][2*512]
  ushort* B_gw0  = (ushort*)alloc(1024ull * 128 * 2);      // [1024][2*64]
  ushort* B_gw1  = (ushort*)alloc(512ull * 2048 * 2);      // [512][2*1024]
  ushort* B_gw2  = (ushort*)alloc(256ull * 1024 * 2);      // [256][2*512]
  ushort* A_h0   = (ushort*)alloc(8192ull * 2048 * 2);     // [8192][2*1024]
  ushort* A_h1   = (ushort*)alloc(8192ull * 1024 * 2);     // [8192][2*512]
  float*  h2     = (float*)alloc(8192ull * 256 * 4);       // [8192][256]
  float*  wts    = (float*)alloc(8192ull * 8 * 4);
  float*  ret    = (float*)alloc(8192ull * 8 * 4);
  (void)ws_size; (void)in_sizes; (void)n_in; (void)out_size;

  // prep activations + weights
  prep_act<<<dim3((8192 * 512 + 255) / 256), 256, 0, stream>>>(obs, A_obs, 8192 * 512, 512);
  prep_act<<<dim3((8192 * 64 + 255) / 256), 256, 0, stream>>>(code, A_code, 8192 * 64, 64);
  prep_w<<<dim3(1024 / 32, 512 / 32, 8), dim3(32, 8), 0, stream>>>(ew0, B_ew0, 512, 1024);
  prep_w<<<dim3(512 / 32, 1024 / 32, 8), dim3(32, 8), 0, stream>>>(ew1, B_ew1, 1024, 512);
  prep_w<<<dim3(256 / 32, 512 / 32, 8), dim3(32, 8), 0, stream>>>(ew2, B_ew2, 512, 256);
  prep_w<<<dim3(1024 / 32, 64 / 32, 1), dim3(32, 8), 0, stream>>>(gw0, B_gw0, 64, 1024);
  prep_w<<<dim3(512 / 32, 1024 / 32, 1), dim3(32, 8), 0, stream>>>(gw1, B_gw1, 1024, 512);
  prep_w<<<dim3(256 / 32, 512 / 32, 1), dim3(32, 8), 0, stream>>>(gw2, B_gw2, 512, 256);

  // gate chain (reuses big activation buffers before experts)
  gemm_bt<0><<<dim3(8, 64), 256, 0, stream>>>(A_code, B_gw0, gb0, A_h0, 1024, 64);
  gemm_bt<0><<<dim3(4, 64), 256, 0, stream>>>(A_h0, B_gw1, gb1, A_h1, 512, 1024);
  gemm_bt<1><<<dim3(2, 64), 256, 0, stream>>>(A_h1, B_gw2, gb2, h2, 256, 512);
  gate3_softmax<<<dim3(8192 / 4), 256, 0, stream>>>(h2, gw3, gb3, wts);

  // experts, sequential
  for (int e = 0; e < 8; ++e){
    gemm_bt<0><<<dim3(8, 64), 256, 0, stream>>>(A_obs, B_ew0 + (size_t)e * 1024 * 1024,
                                                eb0 + e * 1024, A_h0, 1024, 512);
    gemm_bt<0><<<dim3(4, 64), 256, 0, stream>>>(A_h0, B_ew1 + (size_t)e * 512 * 2048,
                                                eb1 + e * 512, A_h1, 512, 1024);
    gemm_bt<1><<<dim3(2, 64), 256, 0, stream>>>(A_h1, B_ew2 + (size_t)e * 256 * 1024,
                                                eb2 + e * 256, h2, 256, 512);
    returns_k<<<dim3(8192 / 4), 256, 0, stream>>>(h2, ew3 + (size_t)e * 256, eb3 + e, ret, e);
  }

  combine<<<dim3(8192 / 256), 256, 0, stream>>>(wts, ret, (float*)d_out);
}

// Round 2
// 982.249 us; speedup vs baseline: 1.4695x; 1.4695x over previous
//
#include <hip/hip_runtime.h>
#include <hip/hip_bf16.h>
#include <math.h>

// B=8192, D=512, V=64, E=8, hidden (1024,512,256)
// All matmuls as bf16 MFMA with hi/lo split (3-product emulation of f32).
// A buffers: [M][2K] bf16 = [hi | lo]. B buffers: [N][2K] bf16 = [hi | lo] (transposed).
// GEMM runs K' = 3K tiles: section 0: Ahi*Bhi, 1: Alo*Bhi, 2: Ahi*Blo.
// This round: batch the 8 expert chains (+gate L1/L2 as 9th slice) into z-sliced
// dispatches, with bijective XCD-chunked block swizzle. Group size G adapts to ws_size.

typedef short bf16x8 __attribute__((ext_vector_type(8)));
typedef float f32x4 __attribute__((ext_vector_type(4)));

__device__ __forceinline__ ushort f2bf(float x){
  union { float f; unsigned u; } v; v.f = x;
  unsigned r = v.u + 0x7fffu + ((v.u >> 16) & 1u);
  return (ushort)(r >> 16);
}
__device__ __forceinline__ float bf2f(ushort h){
  union { unsigned u; float f; } v; v.u = ((unsigned)h) << 16; return v.f;
}
__device__ __forceinline__ float elu_f(float x){
  return x > 0.f ? x : expm1f(x);
}

// ---- prep: activations f32 [rows][K] -> [rows][2K] bf16 hi|lo ----
__global__ void prep_act(const float* __restrict__ X, ushort* __restrict__ A,
                         int total, int K){
  int i = blockIdx.x * blockDim.x + threadIdx.x;
  if (i >= total) return;
  int row = i / K, k = i - row * K;
  float x = X[i];
  ushort hi = f2bf(x);
  ushort lo = f2bf(x - bf2f(hi));
  size_t base = (size_t)row * (size_t)(2 * K);
  A[base + k] = hi;
  A[base + K + k] = lo;
}

// ---- prep: weights f32 [E][K][N] -> Bt bf16 [E][N][2K] (transpose + split) ----
__global__ void prep_w(const float* __restrict__ W, ushort* __restrict__ Bt,
                       int K, int N){
  __shared__ float tile[32][33];
  int e = blockIdx.z;
  const float* w = W + (size_t)e * K * N;
  ushort* bt = Bt + (size_t)e * N * 2 * K;
  int n0 = blockIdx.x * 32, k0 = blockIdx.y * 32;
  for (int i = threadIdx.y; i < 32; i += 8)
    tile[i][threadIdx.x] = w[(size_t)(k0 + i) * N + n0 + threadIdx.x];
  __syncthreads();
  for (int j = threadIdx.y; j < 32; j += 8){
    float v = tile[threadIdx.x][j];             // w[k0+tx][n0+j]
    ushort hi = f2bf(v);
    ushort lo = f2bf(v - bf2f(hi));
    size_t base = (size_t)(n0 + j) * (size_t)(2 * K);
    bt[base + k0 + threadIdx.x] = hi;
    bt[base + K + k0 + threadIdx.x] = lo;
  }
}

// ---- batched GEMM: per z-slice C[M,N] = split3(A[M,2K] x Bt[N,2K]^T) + bias, ELU ----
// EPI==0: write split bf16 [M][2N] hi|lo. EPI==1: write f32 [M][N].
struct Slice { const ushort* A; const ushort* Bt; const float* bias; void* C; };
struct SliceArr { Slice s[9]; };

template<int EPI>
__global__ __launch_bounds__(256) void gemm_bt_batched(
    SliceArr args, int N, int K, int log2gx)
{
  __shared__ __align__(16) ushort As[128][64];   // 16KB
  __shared__ __align__(16) ushort Bs[128][64];   // 16KB

  // XCD-chunked bijective swizzle (nwg % 8 == 0 always: gy=64)
  const int nwg  = gridDim.x;
  const int orig = blockIdx.x;
  const int wg   = (orig & 7) * (nwg >> 3) + (orig >> 3);
  const int shift = log2gx + 6;                 // gy = 64
  const int z   = wg >> shift;
  const int rem = wg & ((1 << shift) - 1);
  const int bx  = rem & ((1 << log2gx) - 1);
  const int by  = rem >> log2gx;

  const Slice sl = args.s[z];
  const ushort* __restrict__ A  = sl.A;
  const ushort* __restrict__ Bt = sl.Bt;

  const int tid  = threadIdx.x;
  const int lane = tid & 63;
  const int wave = tid >> 6;
  const int wr = wave >> 1, wc = wave & 1;      // 2x2 waves, 64x64 each
  const int rowBase = by * 128;
  const int colBase = bx * 128;
  const int KB = K >> 6;                        // K/64 tiles per section
  const int lr = lane & 15;
  const int lk = (lane >> 4) << 3;
  const size_t strideA = (size_t)(2 * K);

  f32x4 acc[4][4];
  #pragma unroll
  for (int m = 0; m < 4; m++)
    #pragma unroll
    for (int n = 0; n < 4; n++)
      acc[m][n] = (f32x4){0.f, 0.f, 0.f, 0.f};

  for (int b = 0; b < 3; ++b){
    const int koffA0 = (b == 1) ? K : 0;        // sections: hi, lo, hi
    const int koffB0 = (b == 2) ? K : 0;        // sections: hi, hi, lo
    for (int it = 0; it < KB; ++it){
      const int koffA = koffA0 + (it << 6);
      const int koffB = koffB0 + (it << 6);
      __syncthreads();   // previous tile fully consumed before overwrite
      #pragma unroll
      for (int j = 0; j < 4; j++){
        int L = (j << 11) + (tid << 3);         // bf16-element offset in 128x64 tile
        int r = L >> 6, c = L & 63;
        __builtin_amdgcn_global_load_lds(
          (const __attribute__((address_space(1))) void*)(A + (size_t)(rowBase + r) * strideA + koffA + c),
          (__attribute__((address_space(3))) void*)(&As[0][0] + L), 16, 0, 0);
        __builtin_amdgcn_global_load_lds(
          (const __attribute__((address_space(1))) void*)(Bt + (size_t)(colBase + r) * strideA + koffB + c),
          (__attribute__((address_space(3))) void*)(&Bs[0][0] + L), 16, 0, 0);
      }
      __syncthreads();   // compiler drains vmcnt before barrier
      #pragma unroll
      for (int ks = 0; ks < 2; ks++){
        bf16x8 af[4], bfr[4];
        #pragma unroll
        for (int m = 0; m < 4; m++)
          af[m] = *(const bf16x8*)&As[wr * 64 + m * 16 + lr][ks * 32 + lk];
        #pragma unroll
        for (int n = 0; n < 4; n++)
          bfr[n] = *(const bf16x8*)&Bs[wc * 64 + n * 16 + lr][ks * 32 + lk];
        #pragma unroll
        for (int m = 0; m < 4; m++)
          #pragma unroll
          for (int n = 0; n < 4; n++)
            acc[m][n] = __builtin_amdgcn_mfma_f32_16x16x32_bf16(af[m], bfr[n], acc[m][n], 0, 0, 0);
      }
    }
  }

  // epilogue: C/D layout col=lane&15, row=(lane>>4)*4+reg
  const int r0 = rowBase + wr * 64 + ((lane >> 4) << 2);
  const int c0 = colBase + wc * 64 + lr;
  #pragma unroll
  for (int m = 0; m < 4; m++){
    #pragma unroll
    for (int n = 0; n < 4; n++){
      int col = c0 + n * 16;
      float bv = sl.bias[col];
      #pragma unroll
      for (int r = 0; r < 4; r++){
        int row = r0 + m * 16 + r;
        float v = elu_f(acc[m][n][r] + bv);
        if (EPI == 0){
          ushort hi = f2bf(v);
          ushort lo = f2bf(v - bf2f(hi));
          ushort* C = (ushort*)sl.C;
          size_t base = (size_t)row * (size_t)(2 * N);
          C[base + col] = hi;
          C[base + N + col] = lo;
        } else {
          ((float*)sl.C)[(size_t)row * N + col] = v;
        }
      }
    }
  }
}

// ---- gate final layer + softmax: wts[B][8] = softmax(g2[B][256] @ gw3[256][8] + gb3) ----
__global__ void gate3_softmax(const float* __restrict__ g2, const float* __restrict__ gw3,
                              const float* __restrict__ gb3, float* __restrict__ wts){
  int row = blockIdx.x * 4 + (threadIdx.x >> 6);
  int lane = threadIdx.x & 63;
  const float* g = g2 + (size_t)row * 256;
  float p[8];
  #pragma unroll
  for (int j = 0; j < 8; j++) p[j] = 0.f;
  for (int k = lane; k < 256; k += 64){
    float x = g[k];
    #pragma unroll
    for (int j = 0; j < 8; j++) p[j] += x * gw3[k * 8 + j];
  }
  #pragma unroll
  for (int j = 0; j < 8; j++){
    #pragma unroll
    for (int s = 32; s > 0; s >>= 1) p[j] += __shfl_xor(p[j], s, 64);
  }
  float mx = -1e30f;
  #pragma unroll
  for (int j = 0; j < 8; j++){ p[j] += gb3[j]; mx = fmaxf(mx, p[j]); }
  float sum = 0.f;
  #pragma unroll
  for (int j = 0; j < 8; j++){ p[j] = expf(p[j] - mx); sum += p[j]; }
  float inv = 1.f / sum;
  #pragma unroll
  for (int j = 0; j < 8; j++)
    if (lane == j) wts[(size_t)row * 8 + j] = p[j] * inv;
}

// ---- expert final layer, batched: ret[B][e0+zy] = h2[zy][B][256] @ w3[e] + b3[e] ----
__global__ void returns_batched(const float* __restrict__ h2base, const float* __restrict__ w3all,
                                const float* __restrict__ b3all, float* __restrict__ ret, int e0){
  int zy = blockIdx.y;
  int e = e0 + zy;
  int row = blockIdx.x * 4 + (threadIdx.x >> 6);
  int lane = threadIdx.x & 63;
  const float* h = h2base + (size_t)zy * (8192ull * 256) + (size_t)row * 256;
  const float* w3 = w3all + (size_t)e * 256;
  float s = 0.f;
  for (int k = lane; k < 256; k += 64) s += h[k] * w3[k];
  #pragma unroll
  for (int m = 32; m > 0; m >>= 1) s += __shfl_xor(s, m, 64);
  if (lane == 0) ret[(size_t)row * 8 + e] = s + b3all[e];
}

// ---- final: out[B] = sum_e wts * ret ----
__global__ void combine(const float* __restrict__ wts, const float* __restrict__ ret,
                        float* __restrict__ out){
  int i = blockIdx.x * blockDim.x + threadIdx.x;
  if (i >= 8192) return;
  float s = 0.f;
  #pragma unroll
  for (int j = 0; j < 8; j++) s += wts[(size_t)i * 8 + j] * ret[(size_t)i * 8 + j];
  out[i] = s;
}

extern "C" void kernel_launch(void* const* d_in, const int* in_sizes, int n_in,
                              void* d_out, int out_size, void* d_ws, size_t ws_size,
                              hipStream_t stream){
  const float* obs  = (const float*)d_in[0];
  const float* code = (const float*)d_in[1];
  const float* ew0  = (const float*)d_in[2];
  const float* eb0  = (const float*)d_in[3];
  const float* ew1  = (const float*)d_in[4];
  const float* eb1  = (const float*)d_in[5];
  const float* ew2  = (const float*)d_in[6];
  const float* eb2  = (const float*)d_in[7];
  const float* ew3  = (const float*)d_in[8];
  const float* eb3  = (const float*)d_in[9];
  const float* gw0  = (const float*)d_in[10];
  const float* gb0  = (const float*)d_in[11];
  const float* gw1  = (const float*)d_in[12];
  const float* gb1  = (const float*)d_in[13];
  const float* gw2  = (const float*)d_in[14];
  const float* gb2  = (const float*)d_in[15];
  const float* gw3  = (const float*)d_in[16];
  const float* gb3  = (const float*)d_in[17];
  (void)in_sizes; (void)n_in; (void)out_size;

  char* ws = (char*)d_ws;
  size_t off = 0;
  auto alloc = [&](size_t bytes) -> void* {
    void* p = ws + off;
    off += (bytes + 255) & ~(size_t)255;
    return p;
  };
  ushort* A_obs  = (ushort*)alloc(8192ull * 1024 * 2);     // [8192][2*512]
  ushort* A_code = (ushort*)alloc(8192ull * 128 * 2);      // [8192][2*64]
  ushort* B_ew0  = (ushort*)alloc(8ull * 1024 * 1024 * 2); // [8][1024][2*512]
  ushort* B_ew1  = (ushort*)alloc(8ull * 512 * 2048 * 2);  // [8][512][2*1024]
  ushort* B_ew2  = (ushort*)alloc(8ull * 256 * 1024 * 2);  // [8][256][2*512]
  ushort* B_gw0  = (ushort*)alloc(1024ull * 128 * 2);      // [1024][2*64]
  ushort* B_gw1  = (ushort*)alloc(512ull * 2048 * 2);      // [512][2*1024]
  ushort* B_gw2  = (ushort*)alloc(256ull * 1024 * 2);      // [256][2*512]
  float*  wts    = (float*)alloc(8192ull * 8 * 4);
  float*  ret    = (float*)alloc(8192ull * 8 * 4);

  // per-slice intermediates (slice counts chosen from ws_size)
  const size_t sl0b = 8192ull * 2048 * 2;   // h0 split bf16
  const size_t sl1b = 8192ull * 1024 * 2;   // h1 split bf16
  const size_t sl2b = 8192ull * 256 * 4;    // h2 f32
  const size_t perSlice = sl0b + sl1b + sl2b;
  const size_t fixed = off;
  int G = 0;
  {
    const int cand[4] = {8, 4, 2, 1};
    for (int ci = 0; ci < 4; ci++){
      if (fixed + (size_t)(cand[ci] + 1) * perSlice <= ws_size){ G = cand[ci]; break; }
    }
  }
  const int ns = (G >= 1) ? (G + 1) : 1;
  ushort* A_h0 = (ushort*)alloc((size_t)ns * sl0b);
  ushort* A_h1 = (ushort*)alloc((size_t)ns * sl1b);
  float*  h2f  = (float*)alloc((size_t)ns * sl2b);
  const size_t sl0e = 8192ull * 2048;
  const size_t sl1e = 8192ull * 1024;
  const size_t sl2e = 8192ull * 256;
  const int gsl = ns - 1;   // gate slice index

  auto launch = [&](int epi, int nz, const Slice* sls, int N, int K, int log2gx){
    SliceArr a;
    for (int i = 0; i < 9; i++) a.s[i] = sls[(i < nz) ? i : 0];
    int nwg = (1 << log2gx) * 64 * nz;
    if (epi == 0) gemm_bt_batched<0><<<nwg, 256, 0, stream>>>(a, N, K, log2gx);
    else          gemm_bt_batched<1><<<nwg, 256, 0, stream>>>(a, N, K, log2gx);
  };

  // prep activations + weights
  prep_act<<<dim3((8192 * 512 + 255) / 256), 256, 0, stream>>>(obs, A_obs, 8192 * 512, 512);
  prep_act<<<dim3((8192 * 64 + 255) / 256), 256, 0, stream>>>(code, A_code, 8192 * 64, 64);
  prep_w<<<dim3(1024 / 32, 512 / 32, 8), dim3(32, 8), 0, stream>>>(ew0, B_ew0, 512, 1024);
  prep_w<<<dim3(512 / 32, 1024 / 32, 8), dim3(32, 8), 0, stream>>>(ew1, B_ew1, 1024, 512);
  prep_w<<<dim3(256 / 32, 512 / 32, 8), dim3(32, 8), 0, stream>>>(ew2, B_ew2, 512, 256);
  prep_w<<<dim3(1024 / 32, 64 / 32, 1), dim3(32, 8), 0, stream>>>(gw0, B_gw0, 64, 1024);
  prep_w<<<dim3(512 / 32, 1024 / 32, 1), dim3(32, 8), 0, stream>>>(gw1, B_gw1, 1024, 512);
  prep_w<<<dim3(256 / 32, 512 / 32, 1), dim3(32, 8), 0, stream>>>(gw2, B_gw2, 512, 256);

  // gate L0 (K=64 differs from expert L0, so it runs standalone; writes gate slice)
  {
    Slice g0 = {A_code, B_gw0, gb0, A_h0 + (size_t)gsl * sl0e};
    launch(0, 1, &g0, 1024, 64, 3);
  }

  if (G >= 1){
    for (int base = 0; base < 8; base += G){
      const bool first = (base == 0);
      const int nz = G + (first ? 1 : 0);
      Slice s[9];
      // L0: experts only
      for (int i = 0; i < G; i++){ int e = base + i;
        s[i] = {A_obs, B_ew0 + (size_t)e * 1024 * 1024, eb0 + e * 1024,
                A_h0 + (size_t)i * sl0e}; }
      launch(0, G, s, 1024, 512, 3);
      // L1: experts (+ gate slice in group 0)
      for (int i = 0; i < G; i++){ int e = base + i;
        s[i] = {A_h0 + (size_t)i * sl0e, B_ew1 + (size_t)e * 512 * 2048, eb1 + e * 512,
                A_h1 + (size_t)i * sl1e}; }
      if (first) s[G] = {A_h0 + (size_t)gsl * sl0e, B_gw1, gb1, A_h1 + (size_t)gsl * sl1e};
      launch(0, nz, s, 512, 1024, 2);
      // L2: experts (+ gate slice in group 0)
      for (int i = 0; i < G; i++){ int e = base + i;
        s[i] = {A_h1 + (size_t)i * sl1e, B_ew2 + (size_t)e * 256 * 1024, eb2 + e * 256,
                h2f + (size_t)i * sl2e}; }
      if (first) s[G] = {A_h1 + (size_t)gsl * sl1e, B_gw2, gb2, h2f + (size_t)gsl * sl2e};
      launch(1, nz, s, 256, 512, 1);
      if (first) gate3_softmax<<<dim3(2048), 256, 0, stream>>>(h2f + (size_t)gsl * sl2e, gw3, gb3, wts);
      returns_batched<<<dim3(2048, G), 256, 0, stream>>>(h2f, ew3, eb3, ret, base);
    }
  } else {
    // fully-sequential fallback (single slice set); gate chain first (gsl == 0)
    Slice s;
    s = {A_h0, B_gw1, gb1, A_h1};              launch(0, 1, &s, 512, 1024, 2);
    s = {A_h1, B_gw2, gb2, h2f};               launch(1, 1, &s, 256, 512, 1);
    gate3_softmax<<<dim3(2048), 256, 0, stream>>>(h2f, gw3, gb3, wts);
    for (int e = 0; e < 8; ++e){
      s = {A_obs, B_ew0 + (size_t)e * 1024 * 1024, eb0 + e * 1024, A_h0};
      launch(0, 1, &s, 1024, 512, 3);
      s = {A_h0, B_ew1 + (size_t)e * 512 * 2048, eb1 + e * 512, A_h1};
      launch(0, 1, &s, 512, 1024, 2);
      s = {A_h1, B_ew2 + (size_t)e * 256 * 1024, eb2 + e * 256, h2f};
      launch(1, 1, &s, 256, 512, 1);
      returns_batched<<<dim3(2048, 1), 256, 0, stream>>>(h2f, ew3, eb3, ret, e);
    }
  }

  combine<<<dim3(8192 / 256), 256, 0, stream>>>(wts, ret, (float*)d_out);
}